// Round 14
// baseline (182.700 us; speedup 1.0000x reference)
//
#include <hip/hip_runtime.h>

#define BB 8
#define NN 4096
#define LL 4096
#define CC 256

typedef short bf16x8 __attribute__((ext_vector_type(8)));
typedef _Float16 f16x8 __attribute__((ext_vector_type(8)));
typedef __fp16 hf16x2 __attribute__((ext_vector_type(2)));  // cvt_pkrtz return type
typedef float f32x4 __attribute__((ext_vector_type(4)));

__device__ __forceinline__ short f2bf(float f) {
  union { float f; unsigned u; } v; v.f = f;
  unsigned r = v.u + 0x7fffu + ((v.u >> 16) & 1u);
  return (short)(r >> 16);
}
// 8 consecutive f32 -> bf16x8 MFMA fragment (two float4 loads)
__device__ __forceinline__ bf16x8 ld8(const float* __restrict__ fp) {
  float4 a = *(const float4*)fp;
  float4 b = *(const float4*)(fp + 4);
  bf16x8 r;
  r[0] = f2bf(a.x); r[1] = f2bf(a.y); r[2] = f2bf(a.z); r[3] = f2bf(a.w);
  r[4] = f2bf(b.x); r[5] = f2bf(b.y); r[6] = f2bf(b.z); r[7] = f2bf(b.w);
  return r;
}
// scale an f16x8 V fragment by 8 f32 zi values (f32 mul + pkrtz == kb2 math)
__device__ __forceinline__ f16x8 scale8(f16x8 v, float4 a, float4 b) {
  union { hf16x2 h[4]; f16x8 v; } r;
  r.h[0] = __builtin_amdgcn_cvt_pkrtz((float)v[0] * a.x, (float)v[1] * a.y);
  r.h[1] = __builtin_amdgcn_cvt_pkrtz((float)v[2] * a.z, (float)v[3] * a.w);
  r.h[2] = __builtin_amdgcn_cvt_pkrtz((float)v[4] * b.x, (float)v[5] * b.y);
  r.h[3] = __builtin_amdgcn_cvt_pkrtz((float)v[6] * b.z, (float)v[7] * b.w);
  return r.v;
}

// ---------------------------------------------------------------------------
// Kernel A: projections.  V written DIRECTLY in [b][32 o][l] raw f16 (r13,
// verified); kb2's 64MB transpose round-trip stays deleted.
// ---------------------------------------------------------------------------
__global__ __launch_bounds__(256) void ka_proj(
    const float* __restrict__ graph, const float* __restrict__ img,
    const float* __restrict__ Wq, const float* __restrict__ bq,
    const float* __restrict__ Wk, const float* __restrict__ bk,
    const float* __restrict__ Wv, const float* __restrict__ bv,
    short* __restrict__ Qb, short* __restrict__ Kt, _Float16* __restrict__ Vt2,
    float* __restrict__ Zbuf)
{
  const int tid = threadIdx.x;
  const int w = tid >> 6, lane = tid & 63, lo = lane & 15, q = lane >> 4;
  const int bid = blockIdx.x;
  if (bid < 512) {
    const int b = bid >> 6;
    if (tid < 64) Zbuf[(size_t)b * LL + ((bid & 63) << 6) + tid] = 0.0f;
    const int lt = ((bid & 63) << 6) + (w << 4);
    f32x4 aK0 = {0,0,0,0}, aK1 = {0,0,0,0}, aV0 = {0,0,0,0}, aV1 = {0,0,0,0};
    const float* ib = img + (size_t)b * CC * LL + lt + lo;
    #pragma unroll
    for (int cs = 0; cs < 8; ++cs) {
      const int c0 = cs * 32 + q * 8;
      bf16x8 bi;
      #pragma unroll
      for (int j = 0; j < 8; ++j) bi[j] = f2bf(ib[(size_t)(c0 + j) * LL]);
      bf16x8 wk0 = ld8(Wk + lo * CC + c0);
      bf16x8 wk1 = ld8(Wk + (lo + 16) * CC + c0);
      bf16x8 wv0 = ld8(Wv + lo * CC + c0);
      bf16x8 wv1 = ld8(Wv + (lo + 16) * CC + c0);
      aK0 = __builtin_amdgcn_mfma_f32_16x16x32_bf16(wk0, bi, aK0, 0, 0, 0);
      aK1 = __builtin_amdgcn_mfma_f32_16x16x32_bf16(wk1, bi, aK1, 0, 0, 0);
      aV0 = __builtin_amdgcn_mfma_f32_16x16x32_bf16(wv0, bi, aV0, 0, 0, 0);
      aV1 = __builtin_amdgcn_mfma_f32_16x16x32_bf16(wv1, bi, aV1, 0, 0, 0);
    }
    const float kscale = 0.2550348663f;  // log2(e)/sqrt(32)
    const size_t row = ((size_t)b * LL + lt + lo) * 32;
    short4 s0, s1;
    s0.x = f2bf((aK0[0] + bk[q * 4 + 0]) * kscale);
    s0.y = f2bf((aK0[1] + bk[q * 4 + 1]) * kscale);
    s0.z = f2bf((aK0[2] + bk[q * 4 + 2]) * kscale);
    s0.w = f2bf((aK0[3] + bk[q * 4 + 3]) * kscale);
    s1.x = f2bf((aK1[0] + bk[16 + q * 4 + 0]) * kscale);
    s1.y = f2bf((aK1[1] + bk[16 + q * 4 + 1]) * kscale);
    s1.z = f2bf((aK1[2] + bk[16 + q * 4 + 2]) * kscale);
    s1.w = f2bf((aK1[3] + bk[16 + q * 4 + 3]) * kscale);
    *(short4*)(Kt + row + q * 4) = s0;
    *(short4*)(Kt + row + 16 + q * 4) = s1;
    // V raw -> [b][32 o][l]
    union { hf16x2 h[2]; __fp16 e[4]; } p0, p1;
    p0.h[0] = __builtin_amdgcn_cvt_pkrtz(aV0[0] + bv[q * 4 + 0], aV0[1] + bv[q * 4 + 1]);
    p0.h[1] = __builtin_amdgcn_cvt_pkrtz(aV0[2] + bv[q * 4 + 2], aV0[3] + bv[q * 4 + 3]);
    p1.h[0] = __builtin_amdgcn_cvt_pkrtz(aV1[0] + bv[16 + q * 4 + 0], aV1[1] + bv[16 + q * 4 + 1]);
    p1.h[1] = __builtin_amdgcn_cvt_pkrtz(aV1[2] + bv[16 + q * 4 + 2], aV1[3] + bv[16 + q * 4 + 3]);
    const size_t vbase = (size_t)b * 32 * LL + lt + lo;
    #pragma unroll
    for (int r = 0; r < 4; ++r) {
      Vt2[vbase + (size_t)(q * 4 + r) * LL] = p0.e[r];
      Vt2[vbase + (size_t)(16 + q * 4 + r) * LL] = p1.e[r];
    }
  } else {
    const int t = bid - 512;
    const int b = t >> 6;
    const int nt = ((t & 63) << 6) + (w << 4);
    bf16x8 ag = ld8(graph + ((size_t)b * NN + nt + lo) * 32 + q * 8);
    bf16x8 w0 = ld8(Wq + lo * 32 + q * 8);
    bf16x8 w1 = ld8(Wq + (lo + 16) * 32 + q * 8);
    f32x4 z = {0,0,0,0};
    f32x4 a0 = __builtin_amdgcn_mfma_f32_16x16x32_bf16(ag, w0, z, 0, 0, 0);
    f32x4 a1 = __builtin_amdgcn_mfma_f32_16x16x32_bf16(ag, w1, z, 0, 0, 0);
    const float b0 = bq[lo], b1 = bq[lo + 16];
    #pragma unroll
    for (int r = 0; r < 4; ++r) {
      const size_t rowq = ((size_t)b * NN + nt + q * 4 + r) * 32;
      Qb[rowq + lo] = f2bf(a0[r] + b0);
      Qb[rowq + 16 + lo] = f2bf(a1[r] + b1);
    }
  }
}

// ---------------------------------------------------------------------------
// Kernel B1: partial softmax denominators, 128-l tiles (unchanged from r11).
// ---------------------------------------------------------------------------
__global__ __launch_bounds__(256) void kb1_z(
    const short* __restrict__ Qb, const short* __restrict__ Kt,
    float* __restrict__ Z)
{
  const int tid = threadIdx.x;
  const int w = tid >> 6, lane = tid & 63, lo = lane & 15, q = lane >> 4;
  const int bid = blockIdx.x;
  const int b = bid & 7;           // XCD-partition: one b per XCD
  const int t = bid >> 3;          // 0..127 within the XCD
  const int l0 = (t >> 2) << 7;    // 32 tiles of 128 l
  const int nq = t & 3;
  bf16x8 kf[8];
  #pragma unroll
  for (int f = 0; f < 8; ++f)
    kf[f] = *(const bf16x8*)(Kt + ((size_t)b * LL + l0 + f * 16 + lo) * 32 + q * 8);
  float za[8][4] = {{0}};
  const short* qbase = Qb + ((size_t)b * NN + nq * 1024 + w * 256 + lo) * 32 + q * 8;
  #pragma unroll 4
  for (int it = 0; it < 16; ++it) {
    bf16x8 qf = *(const bf16x8*)(qbase + it * 512);
    #pragma unroll
    for (int f = 0; f < 8; ++f) {
      f32x4 z = {0,0,0,0};
      f32x4 c = __builtin_amdgcn_mfma_f32_16x16x32_bf16(kf[f], qf, z, 0, 0, 0);
      #pragma unroll
      for (int r = 0; r < 4; ++r) za[f][r] += __builtin_amdgcn_exp2f(c[r]);
    }
  }
  #pragma unroll
  for (int m = 1; m < 16; m <<= 1)
    #pragma unroll
    for (int f = 0; f < 8; ++f)
      #pragma unroll
      for (int r = 0; r < 4; ++r)
        za[f][r] += __shfl_xor(za[f][r], m, 64);
  if (lo == 0) {
    #pragma unroll
    for (int f = 0; f < 8; ++f)
      #pragma unroll
      for (int r = 0; r < 4; ++r)
        atomicAdd(&Z[(size_t)b * LL + l0 + f * 16 + q * 4 + r], za[f][r]);
  }
}

// ---------------------------------------------------------------------------
// Kernel Z: Zi = 4096 / Z.  128 KB -> 128 KB; launch count is free (r10).
// ---------------------------------------------------------------------------
__global__ __launch_bounds__(256) void kz_inv(
    const float* __restrict__ Z, float* __restrict__ Zi)
{
  const int i = blockIdx.x * 256 + threadIdx.x;
  Zi[i] = 4096.0f * __builtin_amdgcn_rcpf(Z[i]);
}

// ---------------------------------------------------------------------------
// Kernel C v6: r12's exact structure (P-pack path untouched), but V fragments
// scaled by zi ONCE per lc (32 cvt + 32 mul + 16 pkrtz, reused by all 16 PV
// MFMAs) -- r13's mistake was folding zi into the per-(nq,f) exp2 path (128
// mults/lc, 8x recompute, +10us).  P[n][l]*zi[l] == P[n][l]*(V[o][l]*zi[l]).
// 256 blocks (1/CU, b=bid&7 XCD-pinned) x 512 thr; block = 128 n; wave = 512 l.
// ---------------------------------------------------------------------------
__global__ __launch_bounds__(512) void kc_attn(
    const short* __restrict__ Qb, const short* __restrict__ Kt,
    const _Float16* __restrict__ Vt2, const float* __restrict__ Zi,
    const float* __restrict__ graph, const float* __restrict__ Wc,
    const float* __restrict__ bc, float* __restrict__ out)
{
  __shared__ __align__(16) unsigned char smem[8 * 4608];  // 36864 B
  const int tid = threadIdx.x;
  const int w = tid >> 6, lane = tid & 63, lo = lane & 15, q = lane >> 4;
  const int b = blockIdx.x & 7;               // XCD-pinned: one b per XCD
  const int n0 = ((int)blockIdx.x >> 3) << 7; // 32 n-tiles of 128 rows
  _Float16* Pw = (_Float16*)(smem + w * 4608);  // [32 n][72] per wave
  bf16x8 qf[8];
  #pragma unroll
  for (int nq = 0; nq < 8; ++nq)
    qf[nq] = *(const bf16x8*)(Qb + ((size_t)b * NN + n0 + nq * 16 + lo) * 32 + q * 8);
  f32x4 m[8][2];
  #pragma unroll
  for (int nq = 0; nq < 8; ++nq) {
    m[nq][0] = (f32x4){0,0,0,0};
    m[nq][1] = (f32x4){0,0,0,0};
  }
  const short* ktb = Kt + (size_t)b * LL * 32 + lo * 32 + q * 8;
  const _Float16* vb0 = Vt2 + ((size_t)b * 32 + lo) * LL;
  const _Float16* vb1 = vb0 + (size_t)16 * LL;
  const float* zib = Zi + b * 4096;
  const int lc0 = w * 8;
  for (int lc = lc0; lc < lc0 + 8; ++lc) {
    const int lbase = lc * 64;
    bf16x8 kf[4];
    #pragma unroll
    for (int f = 0; f < 4; ++f)
      kf[f] = *(const bf16x8*)(ktb + (size_t)(lbase + f * 16) * 32);
    // zi for this lc's V fragment lanes (8 consecutive l per lane)
    float4 z0a = *(const float4*)(zib + lbase + q * 8);
    float4 z0b = *(const float4*)(zib + lbase + q * 8 + 4);
    float4 z1a = *(const float4*)(zib + lbase + 32 + q * 8);
    float4 z1b = *(const float4*)(zib + lbase + 32 + q * 8 + 4);
    f16x8 vA0 = scale8(*(const f16x8*)(vb0 + lbase + q * 8), z0a, z0b);
    f16x8 vA1 = scale8(*(const f16x8*)(vb0 + lbase + 32 + q * 8), z1a, z1b);
    f16x8 vB0 = scale8(*(const f16x8*)(vb1 + lbase + q * 8), z0a, z0b);
    f16x8 vB1 = scale8(*(const f16x8*)(vb1 + lbase + 32 + q * 8), z1a, z1b);
    #pragma unroll
    for (int p = 0; p < 4; ++p) {
      #pragma unroll
      for (int h = 0; h < 2; ++h) {
        const int nq = p * 2 + h;
        #pragma unroll
        for (int f = 0; f < 4; ++f) {
          f32x4 z = {0,0,0,0};
          f32x4 c = __builtin_amdgcn_mfma_f32_16x16x32_bf16(kf[f], qf[nq], z, 0, 0, 0);
          union { hf16x2 hh[2]; uint2 u; } pk;
          pk.hh[0] = __builtin_amdgcn_cvt_pkrtz(__builtin_amdgcn_exp2f(c[0]),
                                                __builtin_amdgcn_exp2f(c[1]));
          pk.hh[1] = __builtin_amdgcn_cvt_pkrtz(__builtin_amdgcn_exp2f(c[2]),
                                                __builtin_amdgcn_exp2f(c[3]));
          *(uint2*)&Pw[(h * 16 + lo) * 72 + f * 16 + q * 4] = pk.u;
        }
      }
      #pragma unroll
      for (int h = 0; h < 2; ++h) {
        const int nq = p * 2 + h;
        f16x8 pa0 = *(const f16x8*)&Pw[(h * 16 + lo) * 72 + q * 8];
        f16x8 pa1 = *(const f16x8*)&Pw[(h * 16 + lo) * 72 + 32 + q * 8];
        m[nq][0] = __builtin_amdgcn_mfma_f32_16x16x32_f16(pa0, vA0, m[nq][0], 0, 0, 0);
        m[nq][1] = __builtin_amdgcn_mfma_f32_16x16x32_f16(pa0, vB0, m[nq][1], 0, 0, 0);
        m[nq][0] = __builtin_amdgcn_mfma_f32_16x16x32_f16(pa1, vA1, m[nq][0], 0, 0, 0);
        m[nq][1] = __builtin_amdgcn_mfma_f32_16x16x32_f16(pa1, vB1, m[nq][1], 0, 0, 0);
      }
    }
  }
  // epilogue: 4 passes of 32 n; out[n][o] = graph + bc[o] + Wc@msg/4096
  const int o = lane & 31, nh = lane >> 5;
  float wcr[32];
  #pragma unroll
  for (int c4 = 0; c4 < 8; ++c4) {
    float4 wc4 = *(const float4*)(Wc + o * 32 + c4 * 4);
    wcr[c4 * 4 + 0] = wc4.x * (1.0f / 4096.0f);
    wcr[c4 * 4 + 1] = wc4.y * (1.0f / 4096.0f);
    wcr[c4 * 4 + 2] = wc4.z * (1.0f / 4096.0f);
    wcr[c4 * 4 + 3] = wc4.w * (1.0f / 4096.0f);
  }
  const float bcv = bc[o];
  float* MSw = (float*)(smem + w * 4608);       // [32 n][36] f32, own region
  const float* MS = (const float*)smem;         // 8 regions, stride 1152 f32
  #pragma unroll
  for (int p = 0; p < 4; ++p) {
    __syncthreads();  // prior pass's cross-wave reads (or loop P reads) done
    #pragma unroll
    for (int h = 0; h < 2; ++h) {
      const int nq = p * 2 + h;
      #pragma unroll
      for (int r = 0; r < 4; ++r) {
        MSw[(h * 16 + q * 4 + r) * 36 + lo] = m[nq][0][r];
        MSw[(h * 16 + q * 4 + r) * 36 + 16 + lo] = m[nq][1][r];
      }
    }
    __syncthreads();
    #pragma unroll
    for (int rr = 0; rr < 2; ++rr) {
      const int nr = w * 4 + nh * 2 + rr;  // 0..31
      f32x4 s = {0,0,0,0};
      #pragma unroll
      for (int cc = 0; cc < 8; ++cc) {
        f32x4 a4 = *(const f32x4*)&MS[0 * 1152 + nr * 36 + cc * 4];
        #pragma unroll
        for (int k = 1; k < 8; ++k)
          a4 += *(const f32x4*)&MS[k * 1152 + nr * 36 + cc * 4];
        s[0] += wcr[cc * 4 + 0] * a4[0];
        s[1] += wcr[cc * 4 + 1] * a4[1];
        s[2] += wcr[cc * 4 + 2] * a4[2];
        s[3] += wcr[cc * 4 + 3] * a4[3];
      }
      const size_t idx = ((size_t)b * NN + n0 + p * 32 + nr) * 32 + o;
      out[idx] = s[0] + s[1] + s[2] + s[3] + bcv + graph[idx];
    }
  }
}

// ---------------------------------------------------------------------------
extern "C" void kernel_launch(void* const* d_in, const int* in_sizes, int n_in,
                              void* d_out, int out_size, void* d_ws, size_t ws_size,
                              hipStream_t stream) {
  const float* graph = (const float*)d_in[0];
  const float* img   = (const float*)d_in[1];
  const float* Wq    = (const float*)d_in[2];
  const float* bq    = (const float*)d_in[3];
  const float* Wk    = (const float*)d_in[4];
  const float* bk    = (const float*)d_in[5];
  const float* Wv    = (const float*)d_in[6];
  const float* bv    = (const float*)d_in[7];
  const float* Wc    = (const float*)d_in[8];
  const float* bc    = (const float*)d_in[9];
  char* ws = (char*)d_ws;
  short*    Qb  = (short*)(ws + 0);          // 2 MB   bf16 [B][N][32]
  short*    Kt  = (short*)(ws + 2097152);    // 2 MB   bf16 [B][L][32] (scaled)
  _Float16* Vt2 = (_Float16*)(ws + 4194304); // 2 MB   f16  [B][32][L] (raw V)
  float*    Zb  = (float*)(ws + 6291456);    // 128 KB f32  [B][L]
  float*    Zi  = (float*)(ws + 6422528);    // 128 KB f32  [B][L] = 4096/Z
  ka_proj<<<dim3(1024), dim3(256), 0, stream>>>(graph, img, Wq, bq, Wk, bk, Wv, bv,
                                                Qb, Kt, Vt2, Zb);
  kb1_z<<<dim3(1024), dim3(256), 0, stream>>>(Qb, Kt, Zb);
  kz_inv<<<dim3(128), dim3(256), 0, stream>>>(Zb, Zi);
  kc_attn<<<dim3(256), dim3(512), 0, stream>>>(Qb, Kt, Vt2, Zi, graph, Wc, bc,
                                               (float*)d_out);
}

// Round 15
// 176.715 us; speedup vs baseline: 1.0339x; 1.0339x over previous
//
#include <hip/hip_runtime.h>

#define BB 8
#define NN 4096
#define LL 4096
#define CC 256

typedef short bf16x8 __attribute__((ext_vector_type(8)));
typedef _Float16 f16x8 __attribute__((ext_vector_type(8)));
typedef __fp16 hf16x2 __attribute__((ext_vector_type(2)));  // cvt_pkrtz return type
typedef float f32x4 __attribute__((ext_vector_type(4)));

__device__ __forceinline__ short f2bf(float f) {
  union { float f; unsigned u; } v; v.f = f;
  unsigned r = v.u + 0x7fffu + ((v.u >> 16) & 1u);
  return (short)(r >> 16);
}
// 8 consecutive f32 -> bf16x8 MFMA fragment (two float4 loads)
__device__ __forceinline__ bf16x8 ld8(const float* __restrict__ fp) {
  float4 a = *(const float4*)fp;
  float4 b = *(const float4*)(fp + 4);
  bf16x8 r;
  r[0] = f2bf(a.x); r[1] = f2bf(a.y); r[2] = f2bf(a.z); r[3] = f2bf(a.w);
  r[4] = f2bf(b.x); r[5] = f2bf(b.y); r[6] = f2bf(b.z); r[7] = f2bf(b.w);
  return r;
}

// ---------------------------------------------------------------------------
// Kernel A: projections (unchanged).
// ---------------------------------------------------------------------------
__global__ __launch_bounds__(256) void ka_proj(
    const float* __restrict__ graph, const float* __restrict__ img,
    const float* __restrict__ Wq, const float* __restrict__ bq,
    const float* __restrict__ Wk, const float* __restrict__ bk,
    const float* __restrict__ Wv, const float* __restrict__ bv,
    short* __restrict__ Qb, short* __restrict__ Kt, _Float16* __restrict__ Vt,
    float* __restrict__ Zbuf)
{
  const int tid = threadIdx.x;
  const int w = tid >> 6, lane = tid & 63, lo = lane & 15, q = lane >> 4;
  const int bid = blockIdx.x;
  if (bid < 512) {
    const int b = bid >> 6;
    if (tid < 64) Zbuf[(size_t)b * LL + ((bid & 63) << 6) + tid] = 0.0f;
    const int lt = ((bid & 63) << 6) + (w << 4);
    f32x4 aK0 = {0,0,0,0}, aK1 = {0,0,0,0}, aV0 = {0,0,0,0}, aV1 = {0,0,0,0};
    const float* ib = img + (size_t)b * CC * LL + lt + lo;
    #pragma unroll
    for (int cs = 0; cs < 8; ++cs) {
      const int c0 = cs * 32 + q * 8;
      bf16x8 bi;
      #pragma unroll
      for (int j = 0; j < 8; ++j) bi[j] = f2bf(ib[(size_t)(c0 + j) * LL]);
      bf16x8 wk0 = ld8(Wk + lo * CC + c0);
      bf16x8 wk1 = ld8(Wk + (lo + 16) * CC + c0);
      bf16x8 wv0 = ld8(Wv + lo * CC + c0);
      bf16x8 wv1 = ld8(Wv + (lo + 16) * CC + c0);
      aK0 = __builtin_amdgcn_mfma_f32_16x16x32_bf16(wk0, bi, aK0, 0, 0, 0);
      aK1 = __builtin_amdgcn_mfma_f32_16x16x32_bf16(wk1, bi, aK1, 0, 0, 0);
      aV0 = __builtin_amdgcn_mfma_f32_16x16x32_bf16(wv0, bi, aV0, 0, 0, 0);
      aV1 = __builtin_amdgcn_mfma_f32_16x16x32_bf16(wv1, bi, aV1, 0, 0, 0);
    }
    const float kscale = 0.2550348663f;  // log2(e)/sqrt(32)
    const size_t row = ((size_t)b * LL + lt + lo) * 32;
    short4 s0, s1;
    s0.x = f2bf((aK0[0] + bk[q * 4 + 0]) * kscale);
    s0.y = f2bf((aK0[1] + bk[q * 4 + 1]) * kscale);
    s0.z = f2bf((aK0[2] + bk[q * 4 + 2]) * kscale);
    s0.w = f2bf((aK0[3] + bk[q * 4 + 3]) * kscale);
    s1.x = f2bf((aK1[0] + bk[16 + q * 4 + 0]) * kscale);
    s1.y = f2bf((aK1[1] + bk[16 + q * 4 + 1]) * kscale);
    s1.z = f2bf((aK1[2] + bk[16 + q * 4 + 2]) * kscale);
    s1.w = f2bf((aK1[3] + bk[16 + q * 4 + 3]) * kscale);
    *(short4*)(Kt + row + q * 4) = s0;
    *(short4*)(Kt + row + 16 + q * 4) = s1;
    union { hf16x2 h[2]; uint2 u; } p0, p1;
    p0.h[0] = __builtin_amdgcn_cvt_pkrtz(aV0[0] + bv[q * 4 + 0], aV0[1] + bv[q * 4 + 1]);
    p0.h[1] = __builtin_amdgcn_cvt_pkrtz(aV0[2] + bv[q * 4 + 2], aV0[3] + bv[q * 4 + 3]);
    p1.h[0] = __builtin_amdgcn_cvt_pkrtz(aV1[0] + bv[16 + q * 4 + 0], aV1[1] + bv[16 + q * 4 + 1]);
    p1.h[1] = __builtin_amdgcn_cvt_pkrtz(aV1[2] + bv[16 + q * 4 + 2], aV1[3] + bv[16 + q * 4 + 3]);
    *(uint2*)(Vt + row + q * 4) = p0.u;
    *(uint2*)(Vt + row + 16 + q * 4) = p1.u;
  } else {
    const int t = bid - 512;
    const int b = t >> 6;
    const int nt = ((t & 63) << 6) + (w << 4);
    bf16x8 ag = ld8(graph + ((size_t)b * NN + nt + lo) * 32 + q * 8);
    bf16x8 w0 = ld8(Wq + lo * 32 + q * 8);
    bf16x8 w1 = ld8(Wq + (lo + 16) * 32 + q * 8);
    f32x4 z = {0,0,0,0};
    f32x4 a0 = __builtin_amdgcn_mfma_f32_16x16x32_bf16(ag, w0, z, 0, 0, 0);
    f32x4 a1 = __builtin_amdgcn_mfma_f32_16x16x32_bf16(ag, w1, z, 0, 0, 0);
    const float b0 = bq[lo], b1 = bq[lo + 16];
    #pragma unroll
    for (int r = 0; r < 4; ++r) {
      const size_t rowq = ((size_t)b * NN + nt + q * 4 + r) * 32;
      Qb[rowq + lo] = f2bf(a0[r] + b0);
      Qb[rowq + 16 + lo] = f2bf(a1[r] + b1);
    }
  }
}

// ---------------------------------------------------------------------------
// Kernel B1: partial softmax denominators, 128-l tiles (unchanged from r11).
// ---------------------------------------------------------------------------
__global__ __launch_bounds__(256) void kb1_z(
    const short* __restrict__ Qb, const short* __restrict__ Kt,
    float* __restrict__ Z)
{
  const int tid = threadIdx.x;
  const int w = tid >> 6, lane = tid & 63, lo = lane & 15, q = lane >> 4;
  const int bid = blockIdx.x;
  const int b = bid & 7;           // XCD-partition: one b per XCD
  const int t = bid >> 3;          // 0..127 within the XCD
  const int l0 = (t >> 2) << 7;    // 32 tiles of 128 l
  const int nq = t & 3;
  bf16x8 kf[8];
  #pragma unroll
  for (int f = 0; f < 8; ++f)
    kf[f] = *(const bf16x8*)(Kt + ((size_t)b * LL + l0 + f * 16 + lo) * 32 + q * 8);
  float za[8][4] = {{0}};
  const short* qbase = Qb + ((size_t)b * NN + nq * 1024 + w * 256 + lo) * 32 + q * 8;
  #pragma unroll 4
  for (int it = 0; it < 16; ++it) {
    bf16x8 qf = *(const bf16x8*)(qbase + it * 512);
    #pragma unroll
    for (int f = 0; f < 8; ++f) {
      f32x4 z = {0,0,0,0};
      f32x4 c = __builtin_amdgcn_mfma_f32_16x16x32_bf16(kf[f], qf, z, 0, 0, 0);
      #pragma unroll
      for (int r = 0; r < 4; ++r) za[f][r] += __builtin_amdgcn_exp2f(c[r]);
    }
  }
  #pragma unroll
  for (int m = 1; m < 16; m <<= 1)
    #pragma unroll
    for (int f = 0; f < 8; ++f)
      #pragma unroll
      for (int r = 0; r < 4; ++r)
        za[f][r] += __shfl_xor(za[f][r], m, 64);
  if (lo == 0) {
    #pragma unroll
    for (int f = 0; f < 8; ++f)
      #pragma unroll
      for (int r = 0; r < 4; ++r)
        atomicAdd(&Z[(size_t)b * LL + l0 + f * 16 + q * 4 + r], za[f][r]);
  }
}

// ---------------------------------------------------------------------------
// Kernel B2: Vpp[b][o][l] = Vt[b][l][o] * (4096 / Z_l).  Kept: its 9us also
// buys L2-hot V for kc (r13/r14 deletions both regressed: +3.7 / +7.0 us).
// ---------------------------------------------------------------------------
__global__ __launch_bounds__(256) void kb2_scale(
    const _Float16* __restrict__ Vt, const float* __restrict__ Z,
    _Float16* __restrict__ Vpp)
{
  const int tid = threadIdx.x;
  const int b = blockIdx.x >> 6;
  const int l = ((blockIdx.x & 63) << 6) + (tid & 63);
  const int og = tid >> 6;  // 0..3
  const float inv = __builtin_amdgcn_rcpf(Z[(size_t)b * LL + l]) * 4096.0f;
  const f16x8 vv = *(const f16x8*)(Vt + ((size_t)b * LL + l) * 32 + og * 8);
  #pragma unroll
  for (int j = 0; j < 8; ++j)
    Vpp[((size_t)b * 32 + og * 8 + j) * LL + l] = (_Float16)((float)vv[j] * inv);
}

// ---------------------------------------------------------------------------
// Kernel C v4: 128-n tiles (r12, best: 175.7us total).  256 blocks (1/CU,
// b=bid&7 XCD-pinned) x 512 thr (8 waves); block = 128 n; wave = 512 l (8 lc).
// Per-CU K/V traffic 512 KB.  P reused across 4 sub-phases of 2 nq; per-wave
// buffers, no lockstep staging.  Epilogue: 4 passes of 32 n.
// ---------------------------------------------------------------------------
__global__ __launch_bounds__(512) void kc_attn(
    const short* __restrict__ Qb, const short* __restrict__ Kt,
    const _Float16* __restrict__ Vpp, const float* __restrict__ graph,
    const float* __restrict__ Wc, const float* __restrict__ bc,
    float* __restrict__ out)
{
  __shared__ __align__(16) unsigned char smem[8 * 4608];  // 36864 B
  const int tid = threadIdx.x;
  const int w = tid >> 6, lane = tid & 63, lo = lane & 15, q = lane >> 4;
  const int b = blockIdx.x & 7;               // XCD-pinned: one b per XCD
  const int n0 = ((int)blockIdx.x >> 3) << 7; // 32 n-tiles of 128 rows
  _Float16* Pw = (_Float16*)(smem + w * 4608);  // [32 n][72] per wave
  bf16x8 qf[8];
  #pragma unroll
  for (int nq = 0; nq < 8; ++nq)
    qf[nq] = *(const bf16x8*)(Qb + ((size_t)b * NN + n0 + nq * 16 + lo) * 32 + q * 8);
  f32x4 m[8][2];
  #pragma unroll
  for (int nq = 0; nq < 8; ++nq) {
    m[nq][0] = (f32x4){0,0,0,0};
    m[nq][1] = (f32x4){0,0,0,0};
  }
  const short* ktb = Kt + (size_t)b * LL * 32 + lo * 32 + q * 8;
  const _Float16* vb0 = Vpp + ((size_t)b * 32 + lo) * LL;
  const _Float16* vb1 = vb0 + (size_t)16 * LL;
  const int lc0 = w * 8;
  for (int lc = lc0; lc < lc0 + 8; ++lc) {
    const int lbase = lc * 64;
    bf16x8 kf[4];
    #pragma unroll
    for (int f = 0; f < 4; ++f)
      kf[f] = *(const bf16x8*)(ktb + (size_t)(lbase + f * 16) * 32);
    f16x8 vA0 = *(const f16x8*)(vb0 + lbase + q * 8);
    f16x8 vA1 = *(const f16x8*)(vb0 + lbase + 32 + q * 8);
    f16x8 vB0 = *(const f16x8*)(vb1 + lbase + q * 8);
    f16x8 vB1 = *(const f16x8*)(vb1 + lbase + 32 + q * 8);
    #pragma unroll
    for (int p = 0; p < 4; ++p) {
      #pragma unroll
      for (int h = 0; h < 2; ++h) {
        const int nq = p * 2 + h;
        #pragma unroll
        for (int f = 0; f < 4; ++f) {
          f32x4 z = {0,0,0,0};
          f32x4 c = __builtin_amdgcn_mfma_f32_16x16x32_bf16(kf[f], qf[nq], z, 0, 0, 0);
          union { hf16x2 hh[2]; uint2 u; } pk;
          pk.hh[0] = __builtin_amdgcn_cvt_pkrtz(__builtin_amdgcn_exp2f(c[0]),
                                                __builtin_amdgcn_exp2f(c[1]));
          pk.hh[1] = __builtin_amdgcn_cvt_pkrtz(__builtin_amdgcn_exp2f(c[2]),
                                                __builtin_amdgcn_exp2f(c[3]));
          *(uint2*)&Pw[(h * 16 + lo) * 72 + f * 16 + q * 4] = pk.u;
        }
      }
      #pragma unroll
      for (int h = 0; h < 2; ++h) {
        const int nq = p * 2 + h;
        f16x8 pa0 = *(const f16x8*)&Pw[(h * 16 + lo) * 72 + q * 8];
        f16x8 pa1 = *(const f16x8*)&Pw[(h * 16 + lo) * 72 + 32 + q * 8];
        m[nq][0] = __builtin_amdgcn_mfma_f32_16x16x32_f16(pa0, vA0, m[nq][0], 0, 0, 0);
        m[nq][1] = __builtin_amdgcn_mfma_f32_16x16x32_f16(pa0, vB0, m[nq][1], 0, 0, 0);
        m[nq][0] = __builtin_amdgcn_mfma_f32_16x16x32_f16(pa1, vA1, m[nq][0], 0, 0, 0);
        m[nq][1] = __builtin_amdgcn_mfma_f32_16x16x32_f16(pa1, vB1, m[nq][1], 0, 0, 0);
      }
    }
  }
  // epilogue: 4 passes of 32 n; out[n][o] = graph + bc[o] + Wc@msg/4096
  const int o = lane & 31, nh = lane >> 5;
  float wcr[32];
  #pragma unroll
  for (int c4 = 0; c4 < 8; ++c4) {
    float4 wc4 = *(const float4*)(Wc + o * 32 + c4 * 4);
    wcr[c4 * 4 + 0] = wc4.x * (1.0f / 4096.0f);
    wcr[c4 * 4 + 1] = wc4.y * (1.0f / 4096.0f);
    wcr[c4 * 4 + 2] = wc4.z * (1.0f / 4096.0f);
    wcr[c4 * 4 + 3] = wc4.w * (1.0f / 4096.0f);
  }
  const float bcv = bc[o];
  float* MSw = (float*)(smem + w * 4608);       // [32 n][36] f32, own region
  const float* MS = (const float*)smem;         // 8 regions, stride 1152 f32
  #pragma unroll
  for (int p = 0; p < 4; ++p) {
    __syncthreads();  // prior pass's cross-wave reads (or loop P reads) done
    #pragma unroll
    for (int h = 0; h < 2; ++h) {
      const int nq = p * 2 + h;
      #pragma unroll
      for (int r = 0; r < 4; ++r) {
        MSw[(h * 16 + q * 4 + r) * 36 + lo] = m[nq][0][r];
        MSw[(h * 16 + q * 4 + r) * 36 + 16 + lo] = m[nq][1][r];
      }
    }
    __syncthreads();
    #pragma unroll
    for (int rr = 0; rr < 2; ++rr) {
      const int nr = w * 4 + nh * 2 + rr;  // 0..31
      f32x4 s = {0,0,0,0};
      #pragma unroll
      for (int cc = 0; cc < 8; ++cc) {
        f32x4 a4 = *(const f32x4*)&MS[0 * 1152 + nr * 36 + cc * 4];
        #pragma unroll
        for (int k = 1; k < 8; ++k)
          a4 += *(const f32x4*)&MS[k * 1152 + nr * 36 + cc * 4];
        s[0] += wcr[cc * 4 + 0] * a4[0];
        s[1] += wcr[cc * 4 + 1] * a4[1];
        s[2] += wcr[cc * 4 + 2] * a4[2];
        s[3] += wcr[cc * 4 + 3] * a4[3];
      }
      const size_t idx = ((size_t)b * NN + n0 + p * 32 + nr) * 32 + o;
      out[idx] = s[0] + s[1] + s[2] + s[3] + bcv + graph[idx];
    }
  }
}

// ---------------------------------------------------------------------------
extern "C" void kernel_launch(void* const* d_in, const int* in_sizes, int n_in,
                              void* d_out, int out_size, void* d_ws, size_t ws_size,
                              hipStream_t stream) {
  const float* graph = (const float*)d_in[0];
  const float* img   = (const float*)d_in[1];
  const float* Wq    = (const float*)d_in[2];
  const float* bq    = (const float*)d_in[3];
  const float* Wk    = (const float*)d_in[4];
  const float* bk    = (const float*)d_in[5];
  const float* Wv    = (const float*)d_in[6];
  const float* bv    = (const float*)d_in[7];
  const float* Wc    = (const float*)d_in[8];
  const float* bc    = (const float*)d_in[9];
  char* ws = (char*)d_ws;
  short*    Qb  = (short*)(ws + 0);          // 2 MB   bf16 [B][N][32]
  short*    Kt  = (short*)(ws + 2097152);    // 2 MB   bf16 [B][L][32] (scaled)
  _Float16* Vt  = (_Float16*)(ws + 4194304); // 2 MB   f16  [B][L][32]
  _Float16* Vpp = (_Float16*)(ws + 6291456); // 2 MB   f16  [B][32][L] (V*4096/Z)
  float*    Zb  = (float*)(ws + 8388608);    // 128 KB f32  [B][L]
  ka_proj<<<dim3(1024), dim3(256), 0, stream>>>(graph, img, Wq, bq, Wk, bk, Wv, bv,
                                                Qb, Kt, Vt, Zb);
  kb1_z<<<dim3(1024), dim3(256), 0, stream>>>(Qb, Kt, Zb);
  kb2_scale<<<dim3(512), dim3(256), 0, stream>>>(Vt, Zb, Vpp);
  kc_attn<<<dim3(256), dim3(512), 0, stream>>>(Qb, Kt, Vpp, graph, Wc, bc,
                                               (float*)d_out);
}